// Round 9
// baseline (317.046 us; speedup 1.0000x reference)
//
#include <hip/hip_runtime.h>

// CrossHeadProjectionV2: B=1, N=16, T=S=2048, G=1, I=2, M=16.
// out[n,t,s] = sum_m x[m,t,s]*wq[t][m][n]
//            + sum_i kw2[s,i,n] * (sum_m x[m,t,s]*kw1[s,i,m])
//            + x[n,t,s]*kdd[s,n]
// wq folds w+I, qdd diagonal, and the rank-2 q-side update (t-only deps).
//
// R9 = R8 per-thread shape, HALVED block: SBLK 128, 128 threads, 4096 blocks.
// LDS/block 35->19 KB so 8 blocks/CU fit; grid offers 16/CU. Target 4-5
// waves/SIMD (vs 2.3) to hide the ds_read/vmem latency that R1-R8 showed is
// the binding constraint (VALUBusy ~20%, all structural levers falsified).

#define TDIM 2048
#define SDIM 2048
#define TT 8
#define SBLK 128
#define THREADS 128

typedef float vf4 __attribute__((ext_vector_type(4)));

__device__ __forceinline__ void barrier_nodrain() {
  // Drain DS ops only (LDS handoff); leave vmcnt (global prefetch) in flight.
  asm volatile("s_waitcnt lgkmcnt(0)" ::: "memory");
  __builtin_amdgcn_s_barrier();
  asm volatile("" ::: "memory");
}

// Opaque pin: forces v's components into registers; the compiler can no
// longer rematerialize the load that produced them (R8: ~7% win).
__device__ __forceinline__ void pin4(vf4& v) {
  float a = v.x, b = v.y, c = v.z, d = v.w;
  asm volatile("" : "+v"(a), "+v"(b), "+v"(c), "+v"(d));
  v.x = a; v.y = b; v.z = c; v.w = d;
}

// ---- prep: transpose per-s weights to s-minor for coalesced reads ----
// kt1[i*16+m][s] = kw1[s][i][m]; kt2[i*16+n][s] = kw2[s][i][n]; kddt[n][s] = kdd[s][n]
__global__ void chp_prep(const float* __restrict__ kw1, const float* __restrict__ kw2,
                         const float* __restrict__ kdd,
                         float* __restrict__ kt1, float* __restrict__ kt2,
                         float* __restrict__ kddt) {
  int tid = blockIdx.x * blockDim.x + threadIdx.x;  // 0 .. 163839
  if (tid < 65536) {
    int im = tid >> 11, s = tid & 2047;
    kt1[tid] = kw1[s * 32 + im];
  } else if (tid < 131072) {
    int v = tid - 65536;
    int im = v >> 11, s = v & 2047;
    kt2[v] = kw2[s * 32 + im];
  } else if (tid < 163840) {
    int v = tid - 131072;
    int n = v >> 11, s = v & 2047;
    kddt[v] = kdd[s * 16 + n];
  }
}

__device__ __forceinline__ vf4 ld4(const float* p) {
  return *reinterpret_cast<const vf4*>(p);
}
__device__ __forceinline__ void fma4(vf4& d, const vf4& a, const vf4& b) {
  d.x = fmaf(a.x, b.x, d.x); d.y = fmaf(a.y, b.y, d.y);
  d.z = fmaf(a.z, b.z, d.z); d.w = fmaf(a.w, b.w, d.w);
}
__device__ __forceinline__ void fma4s(vf4& d, const vf4& a, float b) {
  d.x = fmaf(a.x, b, d.x); d.y = fmaf(a.y, b, d.y);
  d.z = fmaf(a.z, b, d.z); d.w = fmaf(a.w, b, d.w);
}

template <bool KT>
__global__ __launch_bounds__(THREADS, 4) void chp_main(
    const float* __restrict__ in, const float* __restrict__ w,
    const float* __restrict__ qw1, const float* __restrict__ qw2,
    const float* __restrict__ qdd, const float* __restrict__ kw1,
    const float* __restrict__ kw2, const float* __restrict__ kdd,
    const float* __restrict__ kt1, const float* __restrict__ kt2,
    const float* __restrict__ kddt, float* __restrict__ out) {
  // x_lds[buf][m][quad], rows padded to 33 quads to stagger banks.
  __shared__ vf4 x_lds[2][16][33];
  __shared__ float wq_lds[2][256];

  const int tid = threadIdx.x;
  const int j = tid & 3;        // n-slot: owns n,m in {4j..4j+3}
  const int qg = tid >> 2;      // s-quad within block: 0..31
  const int s0 = blockIdx.x * SBLK + qg * 4;
  const int t0 = blockIdx.y * TT;

  // ---- per-block register weights (own 4 rows, own s-quad), loaded ONCE ----
  vf4 kt1v[2][4], kt2v[2][4], kdv[4];
  if constexpr (KT) {
#pragma unroll
    for (int i = 0; i < 2; ++i)
#pragma unroll
      for (int k = 0; k < 4; ++k) {
        kt1v[i][k] = ld4(kt1 + (size_t)(i * 16 + 4 * j + k) * SDIM + s0);
        kt2v[i][k] = ld4(kt2 + (size_t)(i * 16 + 4 * j + k) * SDIM + s0);
      }
#pragma unroll
    for (int k = 0; k < 4; ++k) kdv[k] = ld4(kddt + (size_t)(4 * j + k) * SDIM + s0);
  } else {
#pragma unroll
    for (int i = 0; i < 2; ++i)
#pragma unroll
      for (int k = 0; k < 4; ++k)
#pragma unroll
        for (int c = 0; c < 4; ++c) {
          kt1v[i][k][c] = kw1[(size_t)(s0 + c) * 32 + i * 16 + 4 * j + k];
          kt2v[i][k][c] = kw2[(size_t)(s0 + c) * 32 + i * 16 + 4 * j + k];
        }
#pragma unroll
    for (int k = 0; k < 4; ++k)
#pragma unroll
      for (int c = 0; c < 4; ++c) kdv[k][c] = kdd[(size_t)(s0 + c) * 16 + 4 * j + k];
  }
#pragma unroll
  for (int i = 0; i < 2; ++i)
#pragma unroll
    for (int k = 0; k < 4; ++k) { pin4(kt1v[i][k]); pin4(kt2v[i][k]); }
#pragma unroll
  for (int k = 0; k < 4; ++k) pin4(kdv[k]);

  // wq-build: 128 threads build 256 entries -> 2 each: (bm0,bn), (bm1,bn).
  const int bn = tid & 15;
  const int bm0 = tid >> 4;       // 0..7
  const int bm1 = bm0 + 8;        // 8..15
  const float wbase0 = w[bm0 * 16 + bn];
  const float wbase1 = w[bm1 * 16 + bn];

  vf4 xp[4];
  float q1a0, q1b0, q1a1, q1b1, q2a, q2b, qd;

  auto prefetch = [&](int t) {
#pragma unroll
    for (int k = 0; k < 4; ++k)
      xp[k] = ld4(in + ((size_t)(4 * j + k) * TDIM + t) * SDIM + s0);
    q1a0 = qw1[t * 32 + bm0];
    q1b0 = qw1[t * 32 + 16 + bm0];
    q1a1 = qw1[t * 32 + bm1];
    q1b1 = qw1[t * 32 + 16 + bm1];
    q2a = qw2[t * 32 + bn];
    q2b = qw2[t * 32 + 16 + bn];
    qd = qdd[t * 16 + bn];
  };
  auto stage = [&](int buf) {
#pragma unroll
    for (int k = 0; k < 4; ++k) x_lds[buf][4 * j + k][qg] = xp[k];
    float v0 = fmaf(q1a0, q2a, fmaf(q1b0, q2b, wbase0));
    if (bm0 == bn) v0 += 1.0f + qd;
    wq_lds[buf][tid] = v0;
    float v1 = fmaf(q1a1, q2a, fmaf(q1b1, q2b, wbase1));
    if (bm1 == bn) v1 += 1.0f + qd;
    wq_lds[buf][tid + 128] = v1;
  };

  // ---- prologue: prefetch + stage t0, prefetch t0+1 ----
  prefetch(t0);
  stage(0);
  prefetch(t0 + 1);
  barrier_nodrain();

  int cur = 0;
  for (int tt = 0; tt < TT; ++tt) {
    const int t = t0 + tt;
    const int nxt = cur ^ 1;

    // ---- compute t from LDS buf[cur] ----
    vf4 acc[4];
    vf4 p0 = (vf4){0.f, 0.f, 0.f, 0.f}, p1 = p0;
#pragma unroll
    for (int r = 0; r < 4; ++r) acc[r] = (vf4){0.f, 0.f, 0.f, 0.f};

#pragma unroll
    for (int m = 0; m < 16; ++m) {
      const vf4 xm = x_lds[cur][m][qg];
      const vf4 wr = *reinterpret_cast<const vf4*>(&wq_lds[cur][m * 16 + 4 * j]);
      fma4s(acc[0], xm, wr.x);
      fma4s(acc[1], xm, wr.y);
      fma4s(acc[2], xm, wr.z);
      fma4s(acc[3], xm, wr.w);
      if ((m >> 2) == j) {  // own rows: hk partials + k-diag
        const int k = m & 3;
        fma4(p0, xm, kt1v[0][k]);
        fma4(p1, xm, kt1v[1][k]);
        fma4(acc[k], xm, kdv[k]);
      }
    }
    // butterfly over the 4 j-lanes (lanes 4q..4q+3): full hk at every lane
#pragma unroll
    for (int mask = 1; mask <= 2; mask <<= 1) {
      p0.x += __shfl_xor(p0.x, mask); p0.y += __shfl_xor(p0.y, mask);
      p0.z += __shfl_xor(p0.z, mask); p0.w += __shfl_xor(p0.w, mask);
      p1.x += __shfl_xor(p1.x, mask); p1.y += __shfl_xor(p1.y, mask);
      p1.z += __shfl_xor(p1.z, mask); p1.w += __shfl_xor(p1.w, mask);
    }
    // epilogue + stores
#pragma unroll
    for (int r = 0; r < 4; ++r) {
      fma4(acc[r], p0, kt2v[0][r]);
      fma4(acc[r], p1, kt2v[1][r]);
      *reinterpret_cast<vf4*>(out + ((size_t)(4 * j + r) * TDIM + t) * SDIM + s0) =
          acc[r];
    }

    // ---- stage t+1 into buf[nxt], then prefetch t+2 ----
    if (tt + 1 < TT) {
      stage(nxt);
      if (tt + 2 < TT) prefetch(t + 2);
    }
    // DS handoff drained; global prefetch stays in flight.
    barrier_nodrain();
    cur = nxt;
  }
}

extern "C" void kernel_launch(void* const* d_in, const int* in_sizes, int n_in,
                              void* d_out, int out_size, void* d_ws, size_t ws_size,
                              hipStream_t stream) {
  const float* in = (const float*)d_in[0];
  const float* qw1 = (const float*)d_in[1];
  const float* qw2 = (const float*)d_in[2];
  const float* kw1 = (const float*)d_in[3];
  const float* kw2 = (const float*)d_in[4];
  const float* qdd = (const float*)d_in[5];
  const float* kdd = (const float*)d_in[6];
  const float* w = (const float*)d_in[7];
  float* out = (float*)d_out;
  float* ws = (float*)d_ws;

  const bool useKT = (ws_size >= 163840ull * sizeof(float));
  float* kt1 = ws;
  float* kt2 = ws + 65536;
  float* kddt = ws + 131072;

  dim3 grid(SDIM / SBLK, TDIM / TT);  // (16, 256) = 4096 blocks
  if (useKT) {
    hipLaunchKernelGGL(chp_prep, dim3(640), dim3(256), 0, stream, kw1, kw2, kdd, kt1,
                       kt2, kddt);
    hipLaunchKernelGGL((chp_main<true>), grid, dim3(THREADS), 0, stream, in, w, qw1,
                       qw2, qdd, kw1, kw2, kdd, kt1, kt2, kddt, out);
  } else {
    hipLaunchKernelGGL((chp_main<false>), grid, dim3(THREADS), 0, stream, in, w, qw1,
                       qw2, qdd, kw1, kw2, kdd, nullptr, nullptr, nullptr, out);
  }
}

// Round 10
// 150.570 us; speedup vs baseline: 2.1056x; 2.1056x over previous
//
#include <hip/hip_runtime.h>

// CrossHeadProjectionV2: B=1, N=16, T=S=2048, G=1, I=2, M=16.
// out[n,t,s] = sum_m x[m,t,s]*wq[t][m][n]
//            + sum_i kw2[s,i,n] * (sum_m x[m,t,s]*kw1[s,i,m])
//            + x[n,t,s]*kdd[s,n]
//
// R10 = R8 with ONE change: x_lds single-buffered (35.3 -> ~18.9 KB LDS) +
// a second nodrain barrier as read-fence. Pure occupancy A/B: same grid
// (2048 blocks), same SBLK=256/TT=8, same traffic. LDS now admits ~6
// blocks/CU vs 2.3. If dur doesn't move, the ~2.6 TB/s pattern ceiling
// (theory B) is confirmed and R8-class kernels are at the roofline.

#define TDIM 2048
#define SDIM 2048
#define TT 8
#define SBLK 256

typedef float vf4 __attribute__((ext_vector_type(4)));

__device__ __forceinline__ void barrier_nodrain() {
  asm volatile("s_waitcnt lgkmcnt(0)" ::: "memory");
  __builtin_amdgcn_s_barrier();
  asm volatile("" ::: "memory");
}

// Opaque pin: keeps loaded weights register-resident (R8: ~7% win).
__device__ __forceinline__ void pin4(vf4& v) {
  float a = v.x, b = v.y, c = v.z, d = v.w;
  asm volatile("" : "+v"(a), "+v"(b), "+v"(c), "+v"(d));
  v.x = a; v.y = b; v.z = c; v.w = d;
}

// ---- prep: transpose per-s weights to s-minor for coalesced reads ----
__global__ void chp_prep(const float* __restrict__ kw1, const float* __restrict__ kw2,
                         const float* __restrict__ kdd,
                         float* __restrict__ kt1, float* __restrict__ kt2,
                         float* __restrict__ kddt) {
  int tid = blockIdx.x * blockDim.x + threadIdx.x;  // 0 .. 163839
  if (tid < 65536) {
    int im = tid >> 11, s = tid & 2047;
    kt1[tid] = kw1[s * 32 + im];
  } else if (tid < 131072) {
    int v = tid - 65536;
    int im = v >> 11, s = v & 2047;
    kt2[v] = kw2[s * 32 + im];
  } else if (tid < 163840) {
    int v = tid - 131072;
    int n = v >> 11, s = v & 2047;
    kddt[v] = kdd[s * 16 + n];
  }
}

__device__ __forceinline__ vf4 ld4(const float* p) {
  return *reinterpret_cast<const vf4*>(p);
}
__device__ __forceinline__ void fma4(vf4& d, const vf4& a, const vf4& b) {
  d.x = fmaf(a.x, b.x, d.x); d.y = fmaf(a.y, b.y, d.y);
  d.z = fmaf(a.z, b.z, d.z); d.w = fmaf(a.w, b.w, d.w);
}
__device__ __forceinline__ void fma4s(vf4& d, const vf4& a, float b) {
  d.x = fmaf(a.x, b, d.x); d.y = fmaf(a.y, b, d.y);
  d.z = fmaf(a.z, b, d.z); d.w = fmaf(a.w, b, d.w);
}

template <bool KT>
__global__ __launch_bounds__(256, 2) void chp_main(
    const float* __restrict__ in, const float* __restrict__ w,
    const float* __restrict__ qw1, const float* __restrict__ qw2,
    const float* __restrict__ qdd, const float* __restrict__ kw1,
    const float* __restrict__ kw2, const float* __restrict__ kdd,
    const float* __restrict__ kt1, const float* __restrict__ kt2,
    const float* __restrict__ kddt, float* __restrict__ out) {
  // SINGLE-buffered x (padded to 65 quads); wq stays double-buffered (tiny).
  __shared__ vf4 x_lds[16][65];
  __shared__ float wq_lds[2][256];

  const int tid = threadIdx.x;
  const int j = tid & 3;        // n-slot: owns n,m in {4j..4j+3}
  const int qg = tid >> 2;      // s-quad within block: 0..63
  const int s0 = blockIdx.x * SBLK + qg * 4;
  const int t0 = blockIdx.y * TT;

  // ---- per-block register weights (own 4 rows, own s-quad), loaded ONCE ----
  vf4 kt1v[2][4], kt2v[2][4], kdv[4];
  if constexpr (KT) {
#pragma unroll
    for (int i = 0; i < 2; ++i)
#pragma unroll
      for (int k = 0; k < 4; ++k) {
        kt1v[i][k] = ld4(kt1 + (size_t)(i * 16 + 4 * j + k) * SDIM + s0);
        kt2v[i][k] = ld4(kt2 + (size_t)(i * 16 + 4 * j + k) * SDIM + s0);
      }
#pragma unroll
    for (int k = 0; k < 4; ++k) kdv[k] = ld4(kddt + (size_t)(4 * j + k) * SDIM + s0);
  } else {
#pragma unroll
    for (int i = 0; i < 2; ++i)
#pragma unroll
      for (int k = 0; k < 4; ++k)
#pragma unroll
        for (int c = 0; c < 4; ++c) {
          kt1v[i][k][c] = kw1[(size_t)(s0 + c) * 32 + i * 16 + 4 * j + k];
          kt2v[i][k][c] = kw2[(size_t)(s0 + c) * 32 + i * 16 + 4 * j + k];
        }
#pragma unroll
    for (int k = 0; k < 4; ++k)
#pragma unroll
      for (int c = 0; c < 4; ++c) kdv[k][c] = kdd[(size_t)(s0 + c) * 16 + 4 * j + k];
  }
#pragma unroll
  for (int i = 0; i < 2; ++i)
#pragma unroll
    for (int k = 0; k < 4; ++k) { pin4(kt1v[i][k]); pin4(kt2v[i][k]); }
#pragma unroll
  for (int k = 0; k < 4; ++k) pin4(kdv[k]);

  // wq-build role of this thread: entry (bm, bn)
  const int bm = tid >> 4, bn = tid & 15;
  const float wbase = w[bm * 16 + bn];

  // ---- prologue: prefetch + stage t0, prefetch t0+1 ----
  vf4 xp[4];
#pragma unroll
  for (int k = 0; k < 4; ++k)
    xp[k] = ld4(in + ((size_t)(4 * j + k) * TDIM + t0) * SDIM + s0);
  float q1a = qw1[t0 * 32 + bm], q1b = qw1[t0 * 32 + 16 + bm];
  float q2a = qw2[t0 * 32 + bn], q2b = qw2[t0 * 32 + 16 + bn];
  float qd = qdd[t0 * 16 + bn];

#pragma unroll
  for (int k = 0; k < 4; ++k) x_lds[4 * j + k][qg] = xp[k];
  {
    float v = fmaf(q1a, q2a, wbase);
    v = fmaf(q1b, q2b, v);
    if (bm == bn) v += 1.0f + qd;
    wq_lds[0][tid] = v;
  }
  {  // prefetch t0+1
    const int t1 = t0 + 1;
#pragma unroll
    for (int k = 0; k < 4; ++k)
      xp[k] = ld4(in + ((size_t)(4 * j + k) * TDIM + t1) * SDIM + s0);
    q1a = qw1[t1 * 32 + bm]; q1b = qw1[t1 * 32 + 16 + bm];
    q2a = qw2[t1 * 32 + bn]; q2b = qw2[t1 * 32 + 16 + bn];
    qd = qdd[t1 * 16 + bn];
  }
  barrier_nodrain();  // publish t0

  int cur = 0;
  for (int tt = 0; tt < TT; ++tt) {
    const int t = t0 + tt;
    const int nxt = cur ^ 1;

    // ---- compute t from x_lds + wq_lds[cur] ----
    vf4 acc[4];
    vf4 p0 = (vf4){0.f, 0.f, 0.f, 0.f}, p1 = p0;
#pragma unroll
    for (int r = 0; r < 4; ++r) acc[r] = (vf4){0.f, 0.f, 0.f, 0.f};

#pragma unroll
    for (int m = 0; m < 16; ++m) {
      const vf4 xm = x_lds[m][qg];
      const vf4 wr = *reinterpret_cast<const vf4*>(&wq_lds[cur][m * 16 + 4 * j]);
      fma4s(acc[0], xm, wr.x);
      fma4s(acc[1], xm, wr.y);
      fma4s(acc[2], xm, wr.z);
      fma4s(acc[3], xm, wr.w);
      if ((m >> 2) == j) {  // own rows: hk partials + k-diag
        const int k = m & 3;
        fma4(p0, xm, kt1v[0][k]);
        fma4(p1, xm, kt1v[1][k]);
        fma4(acc[k], xm, kdv[k]);
      }
    }
    // butterfly over the 4 j-lanes: full hk at every lane
#pragma unroll
    for (int mask = 1; mask <= 2; mask <<= 1) {
      p0.x += __shfl_xor(p0.x, mask); p0.y += __shfl_xor(p0.y, mask);
      p0.z += __shfl_xor(p0.z, mask); p0.w += __shfl_xor(p0.w, mask);
      p1.x += __shfl_xor(p1.x, mask); p1.y += __shfl_xor(p1.y, mask);
      p1.z += __shfl_xor(p1.z, mask); p1.w += __shfl_xor(p1.w, mask);
    }
    // epilogue + stores
#pragma unroll
    for (int r = 0; r < 4; ++r) {
      fma4(acc[r], p0, kt2v[0][r]);
      fma4(acc[r], p1, kt2v[1][r]);
      *reinterpret_cast<vf4*>(out + ((size_t)(4 * j + r) * TDIM + t) * SDIM + s0) =
          acc[r];
    }

    // READ-FENCE: all waves done reading x_lds for t before overwrite.
    barrier_nodrain();

    // ---- stage t+1 into the single x buffer, then prefetch t+2 ----
    if (tt + 1 < TT) {
#pragma unroll
      for (int k = 0; k < 4; ++k) x_lds[4 * j + k][qg] = xp[k];
      float v = fmaf(q1a, q2a, wbase);
      v = fmaf(q1b, q2b, v);
      if (bm == bn) v += 1.0f + qd;
      wq_lds[nxt][tid] = v;
      if (tt + 2 < TT) {
        const int tp = t + 2;
#pragma unroll
        for (int k = 0; k < 4; ++k)
          xp[k] = ld4(in + ((size_t)(4 * j + k) * TDIM + tp) * SDIM + s0);
        q1a = qw1[tp * 32 + bm]; q1b = qw1[tp * 32 + 16 + bm];
        q2a = qw2[tp * 32 + bn]; q2b = qw2[tp * 32 + 16 + bn];
        qd = qdd[tp * 16 + bn];
      }
    }
    // PUBLISH: staged t+1 visible to all waves; global prefetch in flight.
    barrier_nodrain();
    cur = nxt;
  }
}

extern "C" void kernel_launch(void* const* d_in, const int* in_sizes, int n_in,
                              void* d_out, int out_size, void* d_ws, size_t ws_size,
                              hipStream_t stream) {
  const float* in = (const float*)d_in[0];
  const float* qw1 = (const float*)d_in[1];
  const float* qw2 = (const float*)d_in[2];
  const float* kw1 = (const float*)d_in[3];
  const float* kw2 = (const float*)d_in[4];
  const float* qdd = (const float*)d_in[5];
  const float* kdd = (const float*)d_in[6];
  const float* w = (const float*)d_in[7];
  float* out = (float*)d_out;
  float* ws = (float*)d_ws;

  const bool useKT = (ws_size >= 163840ull * sizeof(float));
  float* kt1 = ws;
  float* kt2 = ws + 65536;
  float* kddt = ws + 131072;

  dim3 grid(SDIM / SBLK, TDIM / TT);  // (8, 256) = 2048 blocks
  if (useKT) {
    hipLaunchKernelGGL(chp_prep, dim3(640), dim3(256), 0, stream, kw1, kw2, kdd, kt1,
                       kt2, kddt);
    hipLaunchKernelGGL((chp_main<true>), grid, dim3(256), 0, stream, in, w, qw1, qw2,
                       qdd, kw1, kw2, kdd, kt1, kt2, kddt, out);
  } else {
    hipLaunchKernelGGL((chp_main<false>), grid, dim3(256), 0, stream, in, w, qw1, qw2,
                       qdd, kw1, kw2, kdd, nullptr, nullptr, nullptr, out);
  }
}